// Round 7
// baseline (625.600 us; speedup 1.0000x reference)
//
#include <hip/hip_runtime.h>

// FM forward, MI355X — INSTRUMENTATION ROUND.
// Production dispatch (REPEAT=1) + a 31x-repeat dispatch that is long
// enough (>103us) to appear above the harness fill kernels in the
// rocprof top-5, giving us fm_fwd's counters for the first time.
// Repeats are idempotent (same deterministic output each time).
constexpr int B     = 16384;
constexpr int F_CAT = 26;
constexpr int CARD  = 100000;
constexpr int F_NUM = 13;
constexpr int D     = 16;

// 32 lanes per row: lane = half*16 + d. half in {0,1} owns features
// [half*13, half*13+13); d owns dim d. 512K threads -> 2048 blocks ->
// 32 waves/CU. interaction = 0.5*(sum_d s_d^2 - SSQ); per-lane s is a
// feature-half sum, combined via shfl_xor(s,16); each dim then appears
// twice -> 0.25 * s_full^2.
template <int REPEAT>
__global__ __launch_bounds__(256) void fm_fwd_k(
    const int*   __restrict__ cat,   // [B, F_CAT]
    const float* __restrict__ num,   // [B, F_NUM]
    const float* __restrict__ Wc,    // [F_CAT, CARD, D]
    const float* __restrict__ bc,    // [F_CAT, CARD]
    const float* __restrict__ Wn,    // [F_NUM, D]
    const float* __restrict__ bn,    // [F_NUM]
    const float* __restrict__ b0,    // [1]
    float*       __restrict__ out)   // [B]
{
    const int tid  = blockIdx.x * blockDim.x + threadIdx.x;
    const int row  = tid >> 5;
    const int l32  = tid & 31;
    const int half = l32 >> 4;
    const int d    = l32 & 15;

    const int fbase = half * 13;
    const int* rowc = cat + row * F_CAT + fbase;

    for (int r = 0; r < REPEAT; ++r) {
        // force a full re-execution (incl. reloads) each repeat
        asm volatile("" ::: "memory");

        // 13 indices for this lane's feature half (uniform across the
        // 16-lane group -> L1 broadcast)
        int idx[13];
#pragma unroll
        for (int i = 0; i < 13; ++i) idx[i] = rowc[i];

        // 1st-order bias gather rides the queue with the Wc gathers
        float acc = 0.f;
        if (d < 13) acc = bc[(size_t)(fbase + d) * CARD + (size_t)idx[d]];

        // 13 independent 4B gathers, all in flight before any use;
        // 16 consecutive lanes cover one contiguous 64B row segment.
        float v[13];
#pragma unroll
        for (int i = 0; i < 13; ++i) {
            v[i] = Wc[((size_t)(fbase + i) * CARD + (size_t)idx[i]) * D + d];
        }

        float s = 0.f, ssq = 0.f;
#pragma unroll
        for (int i = 0; i < 13; ++i) { s += v[i]; ssq += v[i] * v[i]; }

        // numerical features: half 0 folds them into s/ssq; half 1
        // takes the numerical 1st-order bias
        if (half == 0) {
            const float* nr = num + row * F_NUM;
#pragma unroll
            for (int i = 0; i < F_NUM; ++i) {
                const float x  = nr[i];
                const float vx = x * Wn[i * D + d];
                s += vx; ssq += vx * vx;
            }
        } else if (d < 13) {
            acc += num[row * F_NUM + d] * bn[d];
        }

        // combine feature-halves of s_d, then reduce all 32 lanes
        const float s_full = s + __shfl_xor(s, 16);
        float t = 0.25f * s_full * s_full - 0.5f * ssq + acc;
        t += __shfl_xor(t, 1);
        t += __shfl_xor(t, 2);
        t += __shfl_xor(t, 4);
        t += __shfl_xor(t, 8);
        t += __shfl_xor(t, 16);

        if (l32 == 0) out[row] = t + b0[0];
    }
}

extern "C" void kernel_launch(void* const* d_in, const int* in_sizes, int n_in,
                              void* d_out, int out_size, void* d_ws, size_t ws_size,
                              hipStream_t stream) {
    const int*   cat = (const int*)  d_in[0];
    const float* num = (const float*)d_in[1];
    const float* Wc  = (const float*)d_in[2];
    const float* bc  = (const float*)d_in[3];
    const float* Wn  = (const float*)d_in[4];
    const float* bn  = (const float*)d_in[5];
    const float* b0  = (const float*)d_in[6];
    float*       out = (float*)d_out;

    const int threads = B * 32;          // 32 lanes per row
    const int block   = 256;
    const int grid    = threads / block; // 2048 blocks

    // Dispatch 1: production (L3-cold, right after harness re-poison).
    fm_fwd_k<1><<<grid, block, 0, stream>>>(cat, num, Wc, bc, Wn, bn, b0, out);
    // Dispatch 2: 31x repeat (L3-warm) — long enough to enter rocprof
    // top-5 and expose FETCH_SIZE / VALUBusy / Occupancy for this kernel.
    fm_fwd_k<31><<<grid, block, 0, stream>>>(cat, num, Wc, bc, Wn, bn, b0, out);
}

// Round 8
// 226.987 us; speedup vs baseline: 2.7561x; 2.7561x over previous
//
#include <hip/hip_runtime.h>

// FM forward, MI355X — production kernel (round-6 design, instrumentation
// removed). Measured: ~13.3 us warm pass, 43.6 MB HBM line traffic/pass,
// 3.3 TB/s effective random-gather BW (41% of spec peak), VALUBusy 19%.
// The bench total (~227 us) is dominated by ~210 us of harness re-poison
// fills + input restore; the kernel itself is at the random-128B-line
// gather roofline (each 64B embedding row costs one 128B HBM line).
constexpr int B     = 16384;
constexpr int F_CAT = 26;
constexpr int CARD  = 100000;
constexpr int F_NUM = 13;
constexpr int D     = 16;

// 32 lanes per row: lane = half*16 + d. half in {0,1} owns features
// [half*13, half*13+13); d owns dim d. A Wc load instruction's 16
// consecutive lanes cover one contiguous 64B row segment -> one L2
// request per feature gather; 512K threads -> 2048 blocks -> 32 waves/CU.
//
// interaction = 0.5*(sum_d s_d^2 - SSQ). Per-lane s is a feature-half
// sum; combine halves with shfl_xor(s,16) before squaring; each dim then
// appears twice -> weight s_full^2 by 0.25.
__global__ __launch_bounds__(256) void fm_fwd(
    const int*   __restrict__ cat,   // [B, F_CAT]
    const float* __restrict__ num,   // [B, F_NUM]
    const float* __restrict__ Wc,    // [F_CAT, CARD, D]
    const float* __restrict__ bc,    // [F_CAT, CARD]
    const float* __restrict__ Wn,    // [F_NUM, D]
    const float* __restrict__ bn,    // [F_NUM]
    const float* __restrict__ b0,    // [1]
    float*       __restrict__ out)   // [B]
{
    const int tid  = blockIdx.x * blockDim.x + threadIdx.x;
    const int row  = tid >> 5;
    const int l32  = tid & 31;
    const int half = l32 >> 4;
    const int d    = l32 & 15;

    const int fbase = half * 13;
    const int* rowc = cat + row * F_CAT + fbase;

    // 13 indices for this lane's feature half (uniform across the
    // 16-lane group -> L1 broadcast)
    int idx[13];
#pragma unroll
    for (int i = 0; i < 13; ++i) idx[i] = rowc[i];

    // 1st-order bias gather rides the queue with the Wc gathers below
    float acc = 0.f;
    if (d < 13) acc = bc[(size_t)(fbase + d) * CARD + (size_t)idx[d]];

    // 13 independent 4B gathers, all in flight before any use
    float v[13];
#pragma unroll
    for (int i = 0; i < 13; ++i) {
        v[i] = Wc[((size_t)(fbase + i) * CARD + (size_t)idx[i]) * D + d];
    }

    float s = 0.f, ssq = 0.f;
#pragma unroll
    for (int i = 0; i < 13; ++i) { s += v[i]; ssq += v[i] * v[i]; }

    // numerical features: half 0 folds them into s/ssq; half 1 takes
    // the numerical 1st-order bias (load balance; tables L1/L2-hot)
    if (half == 0) {
        const float* nr = num + row * F_NUM;
#pragma unroll
        for (int i = 0; i < F_NUM; ++i) {
            const float x  = nr[i];
            const float vx = x * Wn[i * D + d];
            s += vx; ssq += vx * vx;
        }
    } else if (d < 13) {
        acc += num[row * F_NUM + d] * bn[d];
    }

    // combine the two feature-halves of s_d, then reduce all 32 lanes
    const float s_full = s + __shfl_xor(s, 16);
    float t = 0.25f * s_full * s_full - 0.5f * ssq + acc;
    t += __shfl_xor(t, 1);
    t += __shfl_xor(t, 2);
    t += __shfl_xor(t, 4);
    t += __shfl_xor(t, 8);
    t += __shfl_xor(t, 16);

    if (l32 == 0) out[row] = t + b0[0];
}

extern "C" void kernel_launch(void* const* d_in, const int* in_sizes, int n_in,
                              void* d_out, int out_size, void* d_ws, size_t ws_size,
                              hipStream_t stream) {
    const int*   cat = (const int*)  d_in[0];
    const float* num = (const float*)d_in[1];
    const float* Wc  = (const float*)d_in[2];
    const float* bc  = (const float*)d_in[3];
    const float* Wn  = (const float*)d_in[4];
    const float* bn  = (const float*)d_in[5];
    const float* b0  = (const float*)d_in[6];
    float*       out = (float*)d_out;

    const int threads = B * 32;          // 32 lanes per row
    const int block   = 256;
    const int grid    = threads / block; // 2048 blocks -> 32 waves/CU
    fm_fwd<<<grid, block, 0, stream>>>(cat, num, Wc, bc, Wn, bn, b0, out);
}